// Round 1
// baseline (606.325 us; speedup 1.0000x reference)
//
#include <hip/hip_runtime.h>
#include <math.h>

#define DIMC 128
#define DST 16
#define DIN 256
#define SEQL 2048
#define NB 2

__device__ __forceinline__ float sigmoidf_(float x){ return 1.0f/(1.0f+__expf(-x)); }
__device__ __forceinline__ float siluf_(float x){ return x/(1.0f+__expf(-x)); }
__device__ __forceinline__ float softplusf_(float x){ return (x > 20.0f) ? x : log1pf(__expf(x)); }

// ---------------- K0: weight transposes ----------------
__global__ void k0_prep(const float* __restrict__ nin_w, const float* __restrict__ nin2_w,
                        const float* __restrict__ outw, const float* __restrict__ xpw,
                        float* __restrict__ ninT, float* __restrict__ nin2T,
                        float* __restrict__ WoutT, float* __restrict__ xpwT)
{
    int t = blockIdx.x*blockDim.x + threadIdx.x;
    if (t < DIMC*DIMC){ int k = t>>7, c = t&127; ninT[t] = nin_w[c*DIMC + k]; nin2T[t] = nin2_w[c*DIMC + k]; }
    if (t < DIN*DIMC){ int k = t>>7, c = t&127; WoutT[t] = outw[c*DIN + k]; }   // WoutT[k][c]
    if (t < DIN*40)  { int k = t/40, o = t%40; xpwT[t] = xpw[o*DIN + k]; }      // xpwT[k][o]
}

// ---------------- K1: pre-stage: act = silu(grn(x@ninW.T + b)) ----------------
__global__ __launch_bounds__(128) void k1_pre(const float* __restrict__ xin, const float* __restrict__ ninT,
                                              const float* __restrict__ ninb,
                                              const float* __restrict__ g1g, const float* __restrict__ g1b,
                                              float* __restrict__ act)
{
    int c = threadIdx.x;
    int row0 = blockIdx.x * 4;                 // rows = b*2048+n, 4 per block
    __shared__ float xl[4][DIMC];
    __shared__ float wred[4][2];
    for (int r=0;r<4;r++){
        int row = row0 + r; int b = row >> 11, n = row & 2047;
        xl[r][c] = xin[n*(NB*DIMC) + b*DIMC + c];
    }
    __syncthreads();
    float acc[4] = {0.f,0.f,0.f,0.f};
    for (int k=0;k<DIMC;k++){
        float w = ninT[k*DIMC + c];
        #pragma unroll
        for (int r=0;r<4;r++) acc[r] += xl[r][k]*w;
    }
    float bias = ninb[c];
    #pragma unroll
    for (int r=0;r<4;r++) acc[r] += bias;
    float s[4]; 
    #pragma unroll
    for (int r=0;r<4;r++) s[r] = acc[r]*acc[r];
    #pragma unroll
    for (int m=1;m<64;m<<=1){
        #pragma unroll
        for (int r=0;r<4;r++) s[r] += __shfl_xor(s[r], m);
    }
    int wid = c >> 6;
    if ((c&63)==0){ 
        #pragma unroll
        for (int r=0;r<4;r++) wred[r][wid] = s[r]; 
    }
    __syncthreads();
    float gg = g1g[c], gb = g1b[c];
    for (int r=0;r<4;r++){
        float nn = wred[r][0] + wred[r][1];
        float gx = sqrtf(nn);
        float nx = gx/(gx+1e-6f);
        float v = gg*(acc[r]*nx) + gb + acc[r]/fmaxf(gx,1e-12f);
        act[(row0+r)*DIMC + c] = siluf_(v);
    }
}

// ---------------- K2: in_proj GEMM, both channel-directions at once ----------------
// XZ0[b][l][j] = sum_k u[b,l,k] * ipw[j][k]           (u[b,l,k] = act[b*262144 + k*2048 + l])
// XZ1[b][l][j] = sum_k u[b,l,127-k] * ipw[j][k]
__global__ __launch_bounds__(256) void k2_inproj(const float* __restrict__ act, const float* __restrict__ ipw,
                                                 float* __restrict__ XZ0, float* __restrict__ XZ1)
{
    __shared__ float uT[128][36];     // [k][l-local], pad 36 (16B aligned rows)
    __shared__ float Wt[32][132];     // [k-chunk][j], pad 132
    int t = threadIdx.x;
    int rt = blockIdx.x >> 2;         // 128 row tiles of 32 l
    int ct = blockIdx.x & 3;          // 4 col tiles of 128 j
    int b = rt >> 6; int l0 = (rt & 63) * 32;
    int col0 = ct * 128;
    {   // stage u (transposed global reads: 32-consecutive-l runs)
        int dl = t & 31; int cbase = t >> 5;
        for (int i=0;i<16;i++){
            int cc = cbase + i*8;
            uT[cc][dl] = act[b*262144 + cc*2048 + l0 + dl];
        }
    }
    float a0[4][4], a1[4][4];
    #pragma unroll
    for (int i=0;i<4;i++) 
        #pragma unroll
        for (int j=0;j<4;j++){ a0[i][j]=0.f; a1[i][j]=0.f; }
    int ty = t >> 5, tx = t & 31;
    for (int kc=0; kc<128; kc+=32){
        __syncthreads();
        {   int j = t >> 1; int ks0 = (t & 1) * 16;
            const float* src = &ipw[(col0 + j)*DIMC + kc + ks0];
            for (int i=0;i<16;i++) Wt[ks0 + i][j] = src[i];
        }
        __syncthreads();
        #pragma unroll 8
        for (int ks=0; ks<32; ks++){
            int k = kc + ks;
            float4 lv = *(const float4*)&uT[k][ty*4];
            float4 lf = *(const float4*)&uT[127-k][ty*4];
            float4 wv = *(const float4*)&Wt[ks][tx*4];
            float lva[4] = {lv.x,lv.y,lv.z,lv.w};
            float lfa[4] = {lf.x,lf.y,lf.z,lf.w};
            float wva[4] = {wv.x,wv.y,wv.z,wv.w};
            #pragma unroll
            for (int rr=0;rr<4;rr++)
                #pragma unroll
                for (int cc2=0;cc2<4;cc2++){
                    a0[rr][cc2] += lva[rr]*wva[cc2];
                    a1[rr][cc2] += lfa[rr]*wva[cc2];
                }
        }
    }
    for (int rr=0;rr<4;rr++){
        int l = l0 + ty*4 + rr;
        float4 v0 = make_float4(a0[rr][0],a0[rr][1],a0[rr][2],a0[rr][3]);
        float4 v1 = make_float4(a1[rr][0],a1[rr][1],a1[rr][2],a1[rr][3]);
        *(float4*)&XZ0[(size_t)(b*SEQL + l)*512 + col0 + tx*4] = v0;
        *(float4*)&XZ1[(size_t)(b*SEQL + l)*512 + col0 + tx*4] = v1;
    }
}

// ---------------- K3: conv + silu + x_proj + dt_proj + softplus, all dirs ----------------
__global__ __launch_bounds__(256) void k3_conv_xproj(const float* __restrict__ XZ0, const float* __restrict__ XZ1,
    const float* __restrict__ convw, const float* __restrict__ convb, const float* __restrict__ xpwT,
    const float* __restrict__ dtw, const float* __restrict__ dtb,
    float* __restrict__ xcB, float* __restrict__ deltaB, float* __restrict__ BmB, float* __restrict__ CmB)
{
    int blk = blockIdx.x;
    int lt = blk & 127; int b = (blk>>7)&1; int dir = blk>>8;
    int rev_c = dir & 1, rev_l = (dir>>1)&1;
    const float* XZ = rev_c ? XZ1 : XZ0;
    int l0 = lt*16;
    int t = threadIdx.x;
    int gb = dir*2 + b;
    __shared__ float xcs[16][DIN];
    __shared__ float dts[16][8];
    __shared__ float bcs[16][32];
    int d = t;
    float w0 = convw[d*4+0], w1 = convw[d*4+1], w2 = convw[d*4+2], w3 = convw[d*4+3];
    float cb = convb[d];
    for (int li=0; li<16; li++){
        int l = l0 + li;
        float sacc = cb;
        int lim;
        lim = l-3; if (lim>=0){ int lg = rev_l ? 2047-lim : lim; sacc += w0*XZ[(size_t)(b*SEQL+lg)*512 + d]; }
        lim = l-2; if (lim>=0){ int lg = rev_l ? 2047-lim : lim; sacc += w1*XZ[(size_t)(b*SEQL+lg)*512 + d]; }
        lim = l-1; if (lim>=0){ int lg = rev_l ? 2047-lim : lim; sacc += w2*XZ[(size_t)(b*SEQL+lg)*512 + d]; }
        lim = l;   {           int lg = rev_l ? 2047-lim : lim; sacc += w3*XZ[(size_t)(b*SEQL+lg)*512 + d]; }
        float v = siluf_(sacc);
        xcs[li][d] = v;
        xcB[((size_t)gb*SEQL + l)*DIN + d] = v;
    }
    __syncthreads();
    for (int idx = t; idx < 640; idx += 256){
        int li = idx / 40; int o = idx % 40;
        float sacc = 0.f;
        for (int k=0;k<DIN;k++) sacc += xcs[li][k] * xpwT[k*40 + o];
        if (o < 8) dts[li][o] = sacc;
        else bcs[li][o-8] = sacc;
    }
    __syncthreads();
    {   int li = t >> 4, s = t & 15;
        BmB[((size_t)gb*SEQL + l0+li)*DST + s] = bcs[li][s];
        CmB[((size_t)gb*SEQL + l0+li)*DST + s] = bcs[li][16+s];
    }
    float dwr[8];
    #pragma unroll
    for (int r=0;r<8;r++) dwr[r] = dtw[d*8+r];
    float db = dtb[d];
    for (int li=0; li<16; li++){
        float sacc = db;
        #pragma unroll
        for (int r=0;r<8;r++) sacc += dts[li][r]*dwr[r];
        deltaB[((size_t)gb*SEQL + l0+li)*DIN + d] = softplusf_(sacc);
    }
}

// ---------------- K4: selective scan (sequential over L, LDS-tiled) ----------------
__global__ __launch_bounds__(128) void k4_scan(const float* __restrict__ XZ0, const float* __restrict__ XZ1,
    const float* __restrict__ xcB, const float* __restrict__ deltaB,
    const float* __restrict__ BmB, const float* __restrict__ CmB,
    const float* __restrict__ A_log, const float* __restrict__ ssmD, float* __restrict__ yB)
{
    int blk = blockIdx.x;
    int d8 = blk & 31; int b = (blk>>5)&1; int dir = blk>>6;
    int rev_c = dir&1, rev_l = (dir>>1)&1;
    const float* XZ = rev_c ? XZ1 : XZ0;
    int d0 = d8*8;
    int t = threadIdx.x; int dl = t>>4, s = t&15;
    int gb = dir*2 + b;
    const float* dlt = deltaB + (size_t)gb*SEQL*DIN;
    const float* xcp = xcB   + (size_t)gb*SEQL*DIN;
    const float* Bmp = BmB   + (size_t)gb*SEQL*DST;
    const float* Cmp = CmB   + (size_t)gb*SEQL*DST;
    float*       yp  = yB    + (size_t)gb*SEQL*DIN;
    float A_ds = -__expf(A_log[(d0+dl)*DST + s]);
    float Dv = ssmD[d0+dl];
    __shared__ float sdelta[128][8];
    __shared__ float sxc[128][8];
    __shared__ float sz[128][8];
    __shared__ float sB[128][16];
    __shared__ float sC[128][16];
    __shared__ float sy[128][8];
    float h = 0.f;
    for (int tile=0; tile<16; tile++){
        int l0 = tile*128;
        __syncthreads();
        {   int col = t & 7, r0 = t >> 3;
            for (int p=0;p<8;p++){
                int row = r0 + p*16;
                int l = l0 + row;
                sdelta[row][col] = dlt[(size_t)l*DIN + d0 + col];
                sxc[row][col]    = xcp[(size_t)l*DIN + d0 + col];
                int lg = rev_l ? 2047 - l : l;
                sz[row][col]     = XZ[(size_t)(b*SEQL + lg)*512 + 256 + d0 + col];
            }
            int col16 = t & 15, r16 = t >> 4;
            for (int p=0;p<16;p++){
                int row = r16 + p*8;
                int l = l0 + row;
                sB[row][col16] = Bmp[(size_t)l*DST + col16];
                sC[row][col16] = Cmp[(size_t)l*DST + col16];
            }
        }
        __syncthreads();
        #pragma unroll 4
        for (int r=0;r<128;r++){
            float dv = sdelta[r][dl];
            float xv = sxc[r][dl];
            float bm = sB[r][s];
            float cm = sC[r][s];
            float dA = __expf(dv * A_ds);
            h = dA*h + dv*bm*xv;
            float py = h*cm;
            py += __shfl_xor(py, 1);
            py += __shfl_xor(py, 2);
            py += __shfl_xor(py, 4);
            py += __shfl_xor(py, 8);
            if (s == 0){
                float zv = sz[r][dl];
                sy[r][dl] = (py + xv*Dv) * siluf_(zv);
            }
        }
        __syncthreads();
        {   int col = t & 7, r0 = t >> 3;
            for (int p=0;p<8;p++){
                int row = r0 + p*16;
                yp[(size_t)(l0+row)*DIN + d0 + col] = sy[row][col];
            }
        }
    }
}

// ---------------- K5: out_proj + 4-direction flip-merge + *temp ----------------
__global__ __launch_bounds__(128) void k5_outproj(const float* __restrict__ yB, const float* __restrict__ WoutT,
                                                  const float* __restrict__ temp, float* __restrict__ xm)
{
    int blk = blockIdx.x;
    int b = blk >> 9; int l0 = (blk & 511) * 4;
    int c = threadIdx.x;
    __shared__ float v02[4][DIN], v13[4][DIN];
    for (int li=0; li<4; li++){
        int l = l0+li, lr = 2047-l;
        for (int k=c; k<DIN; k+=128){
            v02[li][k] = yB[((size_t)(0*2+b)*SEQL + l )*DIN + k] + yB[((size_t)(2*2+b)*SEQL + lr)*DIN + k];
            v13[li][k] = yB[((size_t)(1*2+b)*SEQL + l )*DIN + k] + yB[((size_t)(3*2+b)*SEQL + lr)*DIN + k];
        }
    }
    __syncthreads();
    float acc[4] = {0.f,0.f,0.f,0.f};
    for (int k=0;k<DIN;k++){
        float w  = WoutT[k*DIMC + c];
        float wf = WoutT[k*DIMC + (127-c)];
        #pragma unroll
        for (int li=0; li<4; li++) acc[li] += v02[li][k]*w + v13[li][k]*wf;
    }
    float tm = temp[0];
    for (int li=0; li<4; li++)
        xm[((size_t)b*SEQL + l0+li)*DIMC + c] = acc[li]*tm;
}

// ---------------- K6: cosine gate + nin2 GEMM + grn + silu ----------------
__global__ __launch_bounds__(128) void k6_final(const float* __restrict__ xm, const float* __restrict__ act,
    const float* __restrict__ nin2T, const float* __restrict__ nin2b,
    const float* __restrict__ g2g, const float* __restrict__ g2b,
    const float* __restrict__ wgp, float* __restrict__ dout)
{
    int n = blockIdx.x; int c = threadIdx.x;
    int d = n >> 4; int lbase = (n & 15) << 7;
    // out[b,n,c] = xm[b, lbase+c, d]
    float m0 = xm[((size_t)0*SEQL + lbase + c)*DIMC + d];
    float m1 = xm[((size_t)1*SEQL + lbase + c)*DIMC + d];
    float a0 = act[((size_t)0*SEQL + n)*DIMC + c];
    float a1 = act[((size_t)1*SEQL + n)*DIMC + c];
    float s[6] = { m0*a0, m0*m0, a0*a0, m1*a1, m1*m1, a1*a1 };
    #pragma unroll
    for (int msk=1; msk<64; msk<<=1){
        #pragma unroll
        for (int i=0;i<6;i++) s[i] += __shfl_xor(s[i], msk);
    }
    __shared__ float wred[6][2];
    int wid = c >> 6;
    if ((c & 63) == 0){
        #pragma unroll
        for (int i=0;i<6;i++) wred[i][wid] = s[i];
    }
    __syncthreads();
    float dot0 = wred[0][0]+wred[0][1];
    float mm0  = wred[1][0]+wred[1][1];
    float aa0  = wred[2][0]+wred[2][1];
    float dot1 = wred[3][0]+wred[3][1];
    float mm1  = wred[4][0]+wred[4][1];
    float aa1  = wred[5][0]+wred[5][1];
    float cos0 = dot0 / (fmaxf(sqrtf(mm0),1e-8f)*fmaxf(sqrtf(aa0),1e-8f));
    float cos1 = dot1 / (fmaxf(sqrtf(mm1),1e-8f)*fmaxf(sqrtf(aa1),1e-8f));
    float w = sigmoidf_(0.5f*(cos0+cos1));
    float wg = wgp[0];
    __shared__ float g[2][DIMC];
    g[0][c] = wg*w*m0 + (1.0f-w)*a0;
    g[1][c] = wg*w*m1 + (1.0f-w)*a1;
    __syncthreads();
    float o0 = nin2b[c], o1 = nin2b[c];
    for (int k=0;k<DIMC;k++){
        float wv = nin2T[k*DIMC + c];
        o0 += g[0][k]*wv;
        o1 += g[1][k]*wv;
    }
    float q0 = o0*o0, q1 = o1*o1;
    #pragma unroll
    for (int msk=1; msk<64; msk<<=1){ q0 += __shfl_xor(q0,msk); q1 += __shfl_xor(q1,msk); }
    __syncthreads();
    if ((c&63)==0){ wred[0][wid]=q0; wred[1][wid]=q1; }
    __syncthreads();
    float nn0 = wred[0][0]+wred[0][1];
    float nn1 = wred[1][0]+wred[1][1];
    float gx0 = sqrtf(nn0), gx1 = sqrtf(nn1);
    float gg = g2g[c], gb = g2b[c];
    float v0 = gg*(o0*(gx0/(gx0+1e-6f))) + gb + o0/fmaxf(gx0,1e-12f);
    float v1 = gg*(o1*(gx1/(gx1+1e-6f))) + gb + o1/fmaxf(gx1,1e-12f);
    dout[((size_t)0*SEQL + n)*DIMC + c] = siluf_(v0);
    dout[((size_t)1*SEQL + n)*DIMC + c] = siluf_(v1);
}

extern "C" void kernel_launch(void* const* d_in, const int* in_sizes, int n_in,
                              void* d_out, int out_size, void* d_ws, size_t ws_size,
                              hipStream_t stream) {
    const float* xin   = (const float*)d_in[0];
    const float* nin_w = (const float*)d_in[1];
    const float* nin_b = (const float*)d_in[2];
    const float* nin2_w= (const float*)d_in[3];
    const float* nin2_b= (const float*)d_in[4];
    const float* g1g   = (const float*)d_in[5];
    const float* g1b   = (const float*)d_in[6];
    const float* g2g   = (const float*)d_in[7];
    const float* g2b   = (const float*)d_in[8];
    const float* temp  = (const float*)d_in[9];
    const float* wgate = (const float*)d_in[10];
    const float* ipw   = (const float*)d_in[11];
    const float* convw = (const float*)d_in[12];
    const float* convb = (const float*)d_in[13];
    const float* xpw   = (const float*)d_in[14];
    const float* dtw   = (const float*)d_in[15];
    const float* dtb   = (const float*)d_in[16];
    const float* A_log = (const float*)d_in[17];
    const float* ssmD  = (const float*)d_in[18];
    const float* outw  = (const float*)d_in[19];
    float* ws = (float*)d_ws;

    // ws layout (floats); total ~18.43M floats (~74 MB)
    float* act    = ws;                         // 524288
    float* XZ0    = act    + 524288;            // 2097152
    float* XZ1    = XZ0    + 2097152;           // 2097152
    float* xcB    = XZ1    + 2097152;           // 4194304
    float* deltaB = xcB    + 4194304;           // 4194304
    float* BmB    = deltaB + 4194304;           // 262144
    float* CmB    = BmB    + 262144;            // 262144
    float* yB     = CmB    + 262144;            // 4194304
    float* xm     = yB     + 4194304;           // 524288
    float* ninT   = xm     + 524288;            // 16384
    float* nin2T  = ninT   + 16384;             // 16384
    float* WoutT  = nin2T  + 16384;             // 32768
    float* xpwT   = WoutT  + 32768;             // 10240

    float* dout = (float*)d_out;

    hipLaunchKernelGGL(k0_prep, dim3(128), dim3(256), 0, stream,
                       nin_w, nin2_w, outw, xpw, ninT, nin2T, WoutT, xpwT);
    hipLaunchKernelGGL(k1_pre, dim3(1024), dim3(128), 0, stream,
                       xin, ninT, nin_b, g1g, g1b, act);
    hipLaunchKernelGGL(k2_inproj, dim3(512), dim3(256), 0, stream,
                       act, ipw, XZ0, XZ1);
    hipLaunchKernelGGL(k3_conv_xproj, dim3(1024), dim3(256), 0, stream,
                       XZ0, XZ1, convw, convb, xpwT, dtw, dtb, xcB, deltaB, BmB, CmB);
    hipLaunchKernelGGL(k4_scan, dim3(256), dim3(128), 0, stream,
                       XZ0, XZ1, xcB, deltaB, BmB, CmB, A_log, ssmD, yB);
    hipLaunchKernelGGL(k5_outproj, dim3(1024), dim3(128), 0, stream,
                       yB, WoutT, temp, xm);
    hipLaunchKernelGGL(k6_final, dim3(2048), dim3(128), 0, stream,
                       xm, act, nin2T, nin2_b, g2g, g2b, wgate, dout);
}

// Round 3
// 241.563 us; speedup vs baseline: 2.5100x; 2.5100x over previous
//
#include <hip/hip_runtime.h>
#include <math.h>

#define DIMC 128
#define DST 16
#define DIN 256
#define SEQL 2048
#define NB 2
#define CH 64
#define NCH 32

__device__ __forceinline__ float sigmoidf_(float x){ return 1.0f/(1.0f+__expf(-x)); }
__device__ __forceinline__ float siluf_(float x){ return x/(1.0f+__expf(-x)); }
__device__ __forceinline__ float softplusf_(float x){ return (x > 20.0f) ? x : log1pf(__expf(x)); }

// ---------------- K0: weight transposes ----------------
__global__ void k0_prep(const float* __restrict__ nin_w, const float* __restrict__ nin2_w,
                        const float* __restrict__ outw, const float* __restrict__ xpw,
                        float* __restrict__ ninT, float* __restrict__ nin2T,
                        float* __restrict__ WoutT, float* __restrict__ xpwT)
{
    int t = blockIdx.x*blockDim.x + threadIdx.x;
    if (t < DIMC*DIMC){ int k = t>>7, c = t&127; ninT[t] = nin_w[c*DIMC + k]; nin2T[t] = nin2_w[c*DIMC + k]; }
    if (t < DIN*DIMC){ int k = t>>7, c = t&127; WoutT[t] = outw[c*DIN + k]; }   // WoutT[k][c]
    if (t < DIN*40)  { int k = t/40, o = t%40; xpwT[t] = xpw[o*DIN + k]; }      // xpwT[k][o]
}

// ---------------- K1: pre-stage: act = silu(grn(x@ninW.T + b)) ----------------
__global__ __launch_bounds__(128) void k1_pre(const float* __restrict__ xin, const float* __restrict__ ninT,
                                              const float* __restrict__ ninb,
                                              const float* __restrict__ g1g, const float* __restrict__ g1b,
                                              float* __restrict__ act)
{
    int c = threadIdx.x;
    int row0 = blockIdx.x * 4;                 // rows = b*2048+n, 4 per block
    __shared__ float xl[4][DIMC];
    __shared__ float wred[4][2];
    for (int r=0;r<4;r++){
        int row = row0 + r; int b = row >> 11, n = row & 2047;
        xl[r][c] = xin[n*(NB*DIMC) + b*DIMC + c];
    }
    __syncthreads();
    float acc[4] = {0.f,0.f,0.f,0.f};
    for (int k=0;k<DIMC;k++){
        float w = ninT[k*DIMC + c];
        #pragma unroll
        for (int r=0;r<4;r++) acc[r] += xl[r][k]*w;
    }
    float bias = ninb[c];
    #pragma unroll
    for (int r=0;r<4;r++) acc[r] += bias;
    float s[4]; 
    #pragma unroll
    for (int r=0;r<4;r++) s[r] = acc[r]*acc[r];
    #pragma unroll
    for (int m=1;m<64;m<<=1){
        #pragma unroll
        for (int r=0;r<4;r++) s[r] += __shfl_xor(s[r], m);
    }
    int wid = c >> 6;
    if ((c&63)==0){ 
        #pragma unroll
        for (int r=0;r<4;r++) wred[r][wid] = s[r]; 
    }
    __syncthreads();
    float gg = g1g[c], gb = g1b[c];
    for (int r=0;r<4;r++){
        float nn = wred[r][0] + wred[r][1];
        float gx = sqrtf(nn);
        float nx = gx/(gx+1e-6f);
        float v = gg*(acc[r]*nx) + gb + acc[r]/fmaxf(gx,1e-12f);
        act[(row0+r)*DIMC + c] = siluf_(v);
    }
}

// ---------------- K2: in_proj GEMM, both channel-directions at once ----------------
__global__ __launch_bounds__(256) void k2_inproj(const float* __restrict__ act, const float* __restrict__ ipw,
                                                 float* __restrict__ XZ0, float* __restrict__ XZ1)
{
    __shared__ float uT[128][36];
    __shared__ float Wt[32][132];
    int t = threadIdx.x;
    int rt = blockIdx.x >> 2;
    int ct = blockIdx.x & 3;
    int b = rt >> 6; int l0 = (rt & 63) * 32;
    int col0 = ct * 128;
    {
        int dl = t & 31; int cbase = t >> 5;
        for (int i=0;i<16;i++){
            int cc = cbase + i*8;
            uT[cc][dl] = act[b*262144 + cc*2048 + l0 + dl];
        }
    }
    float a0[4][4], a1[4][4];
    #pragma unroll
    for (int i=0;i<4;i++) 
        #pragma unroll
        for (int j=0;j<4;j++){ a0[i][j]=0.f; a1[i][j]=0.f; }
    int ty = t >> 5, tx = t & 31;
    for (int kc=0; kc<128; kc+=32){
        __syncthreads();
        {   int j = t >> 1; int ks0 = (t & 1) * 16;
            const float* src = &ipw[(col0 + j)*DIMC + kc + ks0];
            for (int i=0;i<16;i++) Wt[ks0 + i][j] = src[i];
        }
        __syncthreads();
        #pragma unroll 8
        for (int ks=0; ks<32; ks++){
            int k = kc + ks;
            float4 lv = *(const float4*)&uT[k][ty*4];
            float4 lf = *(const float4*)&uT[127-k][ty*4];
            float4 wv = *(const float4*)&Wt[ks][tx*4];
            float lva[4] = {lv.x,lv.y,lv.z,lv.w};
            float lfa[4] = {lf.x,lf.y,lf.z,lf.w};
            float wva[4] = {wv.x,wv.y,wv.z,wv.w};
            #pragma unroll
            for (int rr=0;rr<4;rr++)
                #pragma unroll
                for (int cc2=0;cc2<4;cc2++){
                    a0[rr][cc2] += lva[rr]*wva[cc2];
                    a1[rr][cc2] += lfa[rr]*wva[cc2];
                }
        }
    }
    for (int rr=0;rr<4;rr++){
        int l = l0 + ty*4 + rr;
        float4 v0 = make_float4(a0[rr][0],a0[rr][1],a0[rr][2],a0[rr][3]);
        float4 v1 = make_float4(a1[rr][0],a1[rr][1],a1[rr][2],a1[rr][3]);
        *(float4*)&XZ0[(size_t)(b*SEQL + l)*512 + col0 + tx*4] = v0;
        *(float4*)&XZ1[(size_t)(b*SEQL + l)*512 + col0 + tx*4] = v1;
    }
}

// ---------------- K3: conv + silu + x_proj + dt_proj + softplus, all dirs ----------------
__global__ __launch_bounds__(256) void k3_conv_xproj(const float* __restrict__ XZ0, const float* __restrict__ XZ1,
    const float* __restrict__ convw, const float* __restrict__ convb, const float* __restrict__ xpwT,
    const float* __restrict__ dtw, const float* __restrict__ dtb,
    float* __restrict__ xcB, float* __restrict__ deltaB, float* __restrict__ BmB, float* __restrict__ CmB)
{
    int blk = blockIdx.x;
    int lt = blk & 127; int b = (blk>>7)&1; int dir = blk>>8;
    int rev_c = dir & 1, rev_l = (dir>>1)&1;
    const float* XZ = rev_c ? XZ1 : XZ0;
    int l0 = lt*16;
    int t = threadIdx.x;
    int gb = dir*2 + b;
    __shared__ float xcs[16][DIN];
    __shared__ float dts[16][8];
    __shared__ float bcs[16][32];
    int d = t;
    float w0 = convw[d*4+0], w1 = convw[d*4+1], w2 = convw[d*4+2], w3 = convw[d*4+3];
    float cb = convb[d];
    for (int li=0; li<16; li++){
        int l = l0 + li;
        float sacc = cb;
        int lim;
        lim = l-3; if (lim>=0){ int lg = rev_l ? 2047-lim : lim; sacc += w0*XZ[(size_t)(b*SEQL+lg)*512 + d]; }
        lim = l-2; if (lim>=0){ int lg = rev_l ? 2047-lim : lim; sacc += w1*XZ[(size_t)(b*SEQL+lg)*512 + d]; }
        lim = l-1; if (lim>=0){ int lg = rev_l ? 2047-lim : lim; sacc += w2*XZ[(size_t)(b*SEQL+lg)*512 + d]; }
        lim = l;   {           int lg = rev_l ? 2047-lim : lim; sacc += w3*XZ[(size_t)(b*SEQL+lg)*512 + d]; }
        float v = siluf_(sacc);
        xcs[li][d] = v;
        xcB[((size_t)gb*SEQL + l)*DIN + d] = v;
    }
    __syncthreads();
    for (int idx = t; idx < 640; idx += 256){
        int li = idx / 40; int o = idx % 40;
        float sacc = 0.f;
        for (int k=0;k<DIN;k++) sacc += xcs[li][k] * xpwT[k*40 + o];
        if (o < 8) dts[li][o] = sacc;
        else bcs[li][o-8] = sacc;
    }
    __syncthreads();
    {   int li = t >> 4, s = t & 15;
        BmB[((size_t)gb*SEQL + l0+li)*DST + s] = bcs[li][s];
        CmB[((size_t)gb*SEQL + l0+li)*DST + s] = bcs[li][16+s];
    }
    float dwr[8];
    #pragma unroll
    for (int r=0;r<8;r++) dwr[r] = dtw[d*8+r];
    float db = dtb[d];
    for (int li=0; li<16; li++){
        float sacc = db;
        #pragma unroll
        for (int r=0;r<8;r++) sacc += dts[li][r]*dwr[r];
        deltaB[((size_t)gb*SEQL + l0+li)*DIN + d] = softplusf_(sacc);
    }
}

// ---------------- K4a: per-chunk scan summaries (P = prod dA, S = local h) ----------------
__global__ __launch_bounds__(128) void k4a_chunk(const float* __restrict__ deltaB, const float* __restrict__ xcB,
    const float* __restrict__ BmB, const float* __restrict__ A_log,
    float* __restrict__ Pbuf, float* __restrict__ Sbuf)
{
    int blk = blockIdx.x;
    int dg = blk & 31; int chunk = (blk>>5) & 31; int gb = blk >> 10;
    int d0 = dg*8;
    int t = threadIdx.x; int dl = t>>4, s = t&15;
    const float* dlt = deltaB + (size_t)gb*SEQL*DIN;
    const float* xcp = xcB   + (size_t)gb*SEQL*DIN;
    const float* Bmp = BmB   + (size_t)gb*SEQL*DST;
    float A_ds = -__expf(A_log[(d0+dl)*DST + s]);
    __shared__ float sdelta[CH][8];
    __shared__ float sxc[CH][8];
    __shared__ float sB[CH][16];
    int l0 = chunk*CH;
    {   int col = t & 7, r0 = t >> 3;
        for (int p=0;p<4;p++){
            int row = r0 + p*16; int l = l0 + row;
            sdelta[row][col] = dlt[(size_t)l*DIN + d0 + col];
            sxc[row][col]    = xcp[(size_t)l*DIN + d0 + col];
        }
        int col16 = t & 15, r16 = t >> 4;
        for (int p=0;p<8;p++){
            int row = r16 + p*8; int l = l0 + row;
            sB[row][col16] = Bmp[(size_t)l*DST + col16];
        }
    }
    __syncthreads();
    float P = 1.f, S = 0.f;
    #pragma unroll 8
    for (int r=0;r<CH;r++){
        float dv = sdelta[r][dl];
        float xv = sxc[r][dl];
        float bm = sB[r][s];
        float dA = __expf(dv * A_ds);
        S = dA*S + dv*bm*xv;
        P *= dA;
    }
    size_t idx = ((size_t)(gb*NCH + chunk)*32 + dg)*128 + t;
    Pbuf[idx] = P;
    Sbuf[idx] = S;
}

// ---------------- K4b: scan over chunk summaries, per series ----------------
__global__ __launch_bounds__(128) void k4b_scan(const float* __restrict__ Pbuf, const float* __restrict__ Sbuf,
                                                float* __restrict__ Hin)
{
    int gb = blockIdx.x >> 5; int dg = blockIdx.x & 31; int t = threadIdx.x;
    float h = 0.f;
    for (int c=0;c<NCH;c++){
        size_t idx = ((size_t)(gb*NCH + c)*32 + dg)*128 + t;
        float P = Pbuf[idx], S = Sbuf[idx];
        Hin[idx] = h;
        h = S + P*h;
    }
}

// ---------------- K4c: output pass per chunk ----------------
__global__ __launch_bounds__(128) void k4c_out(const float* __restrict__ XZ0, const float* __restrict__ XZ1,
    const float* __restrict__ xcB, const float* __restrict__ deltaB,
    const float* __restrict__ BmB, const float* __restrict__ CmB,
    const float* __restrict__ A_log, const float* __restrict__ ssmD,
    const float* __restrict__ Hin, float* __restrict__ yB)
{
    int blk = blockIdx.x;
    int dg = blk & 31; int chunk = (blk>>5) & 31; int gb = blk >> 10;
    int b = gb & 1; int dir = gb >> 1;
    int rev_c = dir&1, rev_l = (dir>>1)&1;
    const float* XZ = rev_c ? XZ1 : XZ0;
    int d0 = dg*8;
    int t = threadIdx.x; int dl = t>>4, s = t&15;
    const float* dlt = deltaB + (size_t)gb*SEQL*DIN;
    const float* xcp = xcB   + (size_t)gb*SEQL*DIN;
    const float* Bmp = BmB   + (size_t)gb*SEQL*DST;
    const float* Cmp = CmB   + (size_t)gb*SEQL*DST;
    float*       yp  = yB    + (size_t)gb*SEQL*DIN;
    float A_ds = -__expf(A_log[(d0+dl)*DST + s]);
    float Dv = ssmD[d0+dl];
    __shared__ float sdelta[CH][8];
    __shared__ float sxc[CH][8];
    __shared__ float sz[CH][8];
    __shared__ float sB[CH][16];
    __shared__ float sC[CH][16];
    __shared__ float sy[CH][8];
    int l0 = chunk*CH;
    {   int col = t & 7, r0 = t >> 3;
        for (int p=0;p<4;p++){
            int row = r0 + p*16; int l = l0 + row;
            sdelta[row][col] = dlt[(size_t)l*DIN + d0 + col];
            sxc[row][col]    = xcp[(size_t)l*DIN + d0 + col];
            int lg = rev_l ? 2047 - l : l;
            sz[row][col]     = XZ[(size_t)(b*SEQL + lg)*512 + 256 + d0 + col];
        }
        int col16 = t & 15, r16 = t >> 4;
        for (int p=0;p<8;p++){
            int row = r16 + p*8; int l = l0 + row;
            sB[row][col16] = Bmp[(size_t)l*DST + col16];
            sC[row][col16] = Cmp[(size_t)l*DST + col16];
        }
    }
    float h = Hin[((size_t)(gb*NCH + chunk)*32 + dg)*128 + t];
    __syncthreads();
    #pragma unroll 4
    for (int r=0;r<CH;r++){
        float dv = sdelta[r][dl];
        float xv = sxc[r][dl];
        float bm = sB[r][s];
        float cm = sC[r][s];
        float dA = __expf(dv * A_ds);
        h = dA*h + dv*bm*xv;
        float py = h*cm;
        py += __shfl_xor(py, 1);
        py += __shfl_xor(py, 2);
        py += __shfl_xor(py, 4);
        py += __shfl_xor(py, 8);
        if (s == 0){
            float zv = sz[r][dl];
            sy[r][dl] = (py + xv*Dv) * siluf_(zv);
        }
    }
    __syncthreads();
    {   int col = t & 7, r0 = t >> 3;
        for (int p=0;p<4;p++){
            int row = r0 + p*16;
            yp[(size_t)(l0+row)*DIN + d0 + col] = sy[row][col];
        }
    }
}

// ---------------- K5: out_proj + 4-direction flip-merge + *temp ----------------
__global__ __launch_bounds__(128) void k5_outproj(const float* __restrict__ yB, const float* __restrict__ WoutT,
                                                  const float* __restrict__ temp, float* __restrict__ xm)
{
    int blk = blockIdx.x;
    int b = blk >> 9; int l0 = (blk & 511) * 4;
    int c = threadIdx.x;
    __shared__ float v02[4][DIN], v13[4][DIN];
    for (int li=0; li<4; li++){
        int l = l0+li, lr = 2047-l;
        for (int k=c; k<DIN; k+=128){
            v02[li][k] = yB[((size_t)(0*2+b)*SEQL + l )*DIN + k] + yB[((size_t)(2*2+b)*SEQL + lr)*DIN + k];
            v13[li][k] = yB[((size_t)(1*2+b)*SEQL + l )*DIN + k] + yB[((size_t)(3*2+b)*SEQL + lr)*DIN + k];
        }
    }
    __syncthreads();
    float acc[4] = {0.f,0.f,0.f,0.f};
    for (int k=0;k<DIN;k++){
        float w  = WoutT[k*DIMC + c];
        float wf = WoutT[k*DIMC + (127-c)];
        #pragma unroll
        for (int li=0; li<4; li++) acc[li] += v02[li][k]*w + v13[li][k]*wf;
    }
    float tm = temp[0];
    for (int li=0; li<4; li++)
        xm[((size_t)b*SEQL + l0+li)*DIMC + c] = acc[li]*tm;
}

// ---------------- K6: cosine gate + nin2 GEMM + grn + silu ----------------
__global__ __launch_bounds__(128) void k6_final(const float* __restrict__ xm, const float* __restrict__ act,
    const float* __restrict__ nin2T, const float* __restrict__ nin2b,
    const float* __restrict__ g2g, const float* __restrict__ g2b,
    const float* __restrict__ wgp, float* __restrict__ dout)
{
    int n = blockIdx.x; int c = threadIdx.x;
    int d = n >> 4; int lbase = (n & 15) << 7;
    float m0 = xm[((size_t)0*SEQL + lbase + c)*DIMC + d];
    float m1 = xm[((size_t)1*SEQL + lbase + c)*DIMC + d];
    float a0 = act[((size_t)0*SEQL + n)*DIMC + c];
    float a1 = act[((size_t)1*SEQL + n)*DIMC + c];
    float s[6] = { m0*a0, m0*m0, a0*a0, m1*a1, m1*m1, a1*a1 };
    #pragma unroll
    for (int msk=1; msk<64; msk<<=1){
        #pragma unroll
        for (int i=0;i<6;i++) s[i] += __shfl_xor(s[i], msk);
    }
    __shared__ float wred[6][2];
    int wid = c >> 6;
    if ((c & 63) == 0){
        #pragma unroll
        for (int i=0;i<6;i++) wred[i][wid] = s[i];
    }
    __syncthreads();
    float dot0 = wred[0][0]+wred[0][1];
    float mm0  = wred[1][0]+wred[1][1];
    float aa0  = wred[2][0]+wred[2][1];
    float dot1 = wred[3][0]+wred[3][1];
    float mm1  = wred[4][0]+wred[4][1];
    float aa1  = wred[5][0]+wred[5][1];
    float cos0 = dot0 / (fmaxf(sqrtf(mm0),1e-8f)*fmaxf(sqrtf(aa0),1e-8f));
    float cos1 = dot1 / (fmaxf(sqrtf(mm1),1e-8f)*fmaxf(sqrtf(aa1),1e-8f));
    float w = sigmoidf_(0.5f*(cos0+cos1));
    float wg = wgp[0];
    __shared__ float g[2][DIMC];
    g[0][c] = wg*w*m0 + (1.0f-w)*a0;
    g[1][c] = wg*w*m1 + (1.0f-w)*a1;
    __syncthreads();
    float o0 = nin2b[c], o1 = nin2b[c];
    for (int k=0;k<DIMC;k++){
        float wv = nin2T[k*DIMC + c];
        o0 += g[0][k]*wv;
        o1 += g[1][k]*wv;
    }
    float q0 = o0*o0, q1 = o1*o1;
    #pragma unroll
    for (int msk=1; msk<64; msk<<=1){ q0 += __shfl_xor(q0,msk); q1 += __shfl_xor(q1,msk); }
    __syncthreads();
    if ((c&63)==0){ wred[0][wid]=q0; wred[1][wid]=q1; }
    __syncthreads();
    float nn0 = wred[0][0]+wred[0][1];
    float nn1 = wred[1][0]+wred[1][1];
    float gx0 = sqrtf(nn0), gx1 = sqrtf(nn1);
    float gg = g2g[c], gb = g2b[c];
    float v0 = gg*(o0*(gx0/(gx0+1e-6f))) + gb + o0/fmaxf(gx0,1e-12f);
    float v1 = gg*(o1*(gx1/(gx1+1e-6f))) + gb + o1/fmaxf(gx1,1e-12f);
    dout[((size_t)0*SEQL + n)*DIMC + c] = siluf_(v0);
    dout[((size_t)1*SEQL + n)*DIMC + c] = siluf_(v1);
}

extern "C" void kernel_launch(void* const* d_in, const int* in_sizes, int n_in,
                              void* d_out, int out_size, void* d_ws, size_t ws_size,
                              hipStream_t stream) {
    const float* xin   = (const float*)d_in[0];
    const float* nin_w = (const float*)d_in[1];
    const float* nin_b = (const float*)d_in[2];
    const float* nin2_w= (const float*)d_in[3];
    const float* nin2_b= (const float*)d_in[4];
    const float* g1g   = (const float*)d_in[5];
    const float* g1b   = (const float*)d_in[6];
    const float* g2g   = (const float*)d_in[7];
    const float* g2b   = (const float*)d_in[8];
    const float* temp  = (const float*)d_in[9];
    const float* wgate = (const float*)d_in[10];
    const float* ipw   = (const float*)d_in[11];
    const float* convw = (const float*)d_in[12];
    const float* convb = (const float*)d_in[13];
    const float* xpw   = (const float*)d_in[14];
    const float* dtw   = (const float*)d_in[15];
    const float* dtb   = (const float*)d_in[16];
    const float* A_log = (const float*)d_in[17];
    const float* ssmD  = (const float*)d_in[18];
    const float* outw  = (const float*)d_in[19];
    float* ws = (float*)d_ws;

    float* act    = ws;                         // 524288
    float* XZ0    = act    + 524288;            // 2097152
    float* XZ1    = XZ0    + 2097152;           // 2097152
    float* xcB    = XZ1    + 2097152;           // 4194304
    float* deltaB = xcB    + 4194304;           // 4194304
    float* BmB    = deltaB + 4194304;           // 262144
    float* CmB    = BmB    + 262144;            // 262144
    float* yB     = CmB    + 262144;            // 4194304
    float* xm     = yB     + 4194304;           // 524288
    float* ninT   = xm     + 524288;            // 16384
    float* nin2T  = ninT   + 16384;             // 16384
    float* WoutT  = nin2T  + 16384;             // 32768
    float* xpwT   = WoutT  + 32768;             // 10240
    float* Pbuf   = xpwT   + 10240;             // 1048576
    float* Sbuf   = Pbuf   + 1048576;           // 1048576
    float* Hin    = Sbuf   + 1048576;           // 1048576

    float* dout = (float*)d_out;

    hipLaunchKernelGGL(k0_prep, dim3(128), dim3(256), 0, stream,
                       nin_w, nin2_w, outw, xpw, ninT, nin2T, WoutT, xpwT);
    hipLaunchKernelGGL(k1_pre, dim3(1024), dim3(128), 0, stream,
                       xin, ninT, nin_b, g1g, g1b, act);
    hipLaunchKernelGGL(k2_inproj, dim3(512), dim3(256), 0, stream,
                       act, ipw, XZ0, XZ1);
    hipLaunchKernelGGL(k3_conv_xproj, dim3(1024), dim3(256), 0, stream,
                       XZ0, XZ1, convw, convb, xpwT, dtw, dtb, xcB, deltaB, BmB, CmB);
    hipLaunchKernelGGL(k4a_chunk, dim3(8192), dim3(128), 0, stream,
                       deltaB, xcB, BmB, A_log, Pbuf, Sbuf);
    hipLaunchKernelGGL(k4b_scan, dim3(256), dim3(128), 0, stream,
                       Pbuf, Sbuf, Hin);
    hipLaunchKernelGGL(k4c_out, dim3(8192), dim3(128), 0, stream,
                       XZ0, XZ1, xcB, deltaB, BmB, CmB, A_log, ssmD, Hin, yB);
    hipLaunchKernelGGL(k5_outproj, dim3(1024), dim3(128), 0, stream,
                       yB, WoutT, temp, xm);
    hipLaunchKernelGGL(k6_final, dim3(2048), dim3(128), 0, stream,
                       xm, act, nin2T, nin2_b, g2g, g2b, wgate, dout);
}